// Round 16
// baseline (210.975 us; speedup 1.0000x reference)
//
#include <hip/hip_runtime.h>
#include <hip/hip_bf16.h>
#include <cstdint>
#include <cstddef>

// ---------- constants ----------
#define BATCH 2
#define CTX 2048
#define EMB 2048
#define NH 16
#define NG 4
#define HD 128
#define NQK (EMB + 2*NG*HD)   // 3072 combined QKV output cols
#define MROWS (BATCH*CTX)     // 4096

typedef __bf16 bf16x8 __attribute__((ext_vector_type(8)));
typedef float  f32x4  __attribute__((ext_vector_type(4)));
typedef float  f32x16 __attribute__((ext_vector_type(16)));

__device__ __forceinline__ ushort f2bf(float f) {
    uint32_t u = __float_as_uint(f);
    u += 0x7FFFu + ((u >> 16) & 1u);   // round-to-nearest-even
    return (ushort)(u >> 16);
}

__device__ __forceinline__ float bf2f(ushort u) {
    return __uint_as_float((uint32_t)u << 16);
}

__device__ __forceinline__ uint32_t packbf(float a, float b) {
    ushort lo = __builtin_bit_cast(ushort, (__bf16)a);
    ushort hi = __builtin_bit_cast(ushort, (__bf16)b);
    return (uint32_t)lo | ((uint32_t)hi << 16);
}

__device__ __forceinline__ bf16x8 mkfrag(uint32_t a, uint32_t b, uint32_t c, uint32_t d) {
    union { uint32_t u[4]; bf16x8 v; } z;
    z.u[0] = a; z.u[1] = b; z.u[2] = c; z.u[3] = d;
    return z.v;
}

__device__ __forceinline__ void gload_lds16(const void* g, void* l) {
    __builtin_amdgcn_global_load_lds((const __attribute__((address_space(1))) void*)g,
                                     (__attribute__((address_space(3))) void*)l, 16, 0, 0);
}

// ---------- sin table: sintab[pos][j], j in 0..63 ----------
__global__ __launch_bounds__(256) void k_sintab(float* __restrict__ sintab) {
    int t = blockIdx.x * 256 + threadIdx.x;   // 2048*64
    int j = t & 63, p = t >> 6;
    float theta = 1.0f / powf(10000.0f, (float)(2 * j) / 64.0f);
    sintab[t] = sinf((float)p * theta);
}

// ---------- f32 -> bf16 elementwise (4 per thread) ----------
__global__ __launch_bounds__(256) void k_cvt(const float4* __restrict__ src, ushort4* __restrict__ dst) {
    int i = blockIdx.x * 256 + threadIdx.x;
    float4 v = src[i];
    ushort4 o;
    o.x = f2bf(v.x); o.y = f2bf(v.y); o.z = f2bf(v.z); o.w = f2bf(v.w);
    dst[i] = o;
}

// ---------- all 4 weight transposes in one launch (z selects) ----------
__global__ __launch_bounds__(256) void k_transpose_all(const float* __restrict__ Wq, const float* __restrict__ Wk,
                                                       const float* __restrict__ Wv, const float* __restrict__ Wo,
                                                       ushort* __restrict__ Wt, ushort* __restrict__ Wot) {
    __shared__ float tile[32][33];
    int z = blockIdx.z;
    const float* src; ushort* dst; int src_ld, dst_ld, ncols;
    if (z == 0)      { src = Wq; dst = Wt;                              src_ld = EMB;   dst_ld = EMB; ncols = EMB; }
    else if (z == 1) { src = Wk; dst = Wt + (size_t)EMB * EMB;          src_ld = NG*HD; dst_ld = EMB; ncols = NG*HD; }
    else if (z == 2) { src = Wv; dst = Wt + (size_t)(EMB + NG*HD) * EMB; src_ld = NG*HD; dst_ld = EMB; ncols = NG*HD; }
    else             { src = Wo; dst = Wot;                             src_ld = EMB;   dst_ld = EMB; ncols = EMB; }
    int c0 = blockIdx.x * 32, r0 = blockIdx.y * 32;
    if (c0 >= ncols) return;
    int tx = threadIdx.x, ty = threadIdx.y;          // 32 x 8
    #pragma unroll
    for (int i = 0; i < 4; ++i)
        tile[ty + i*8][tx] = src[(size_t)(r0 + ty + i*8) * src_ld + c0 + tx];
    __syncthreads();
    #pragma unroll
    for (int i = 0; i < 4; ++i)
        dst[(size_t)(c0 + ty + i*8) * dst_ld + r0 + tx] = f2bf(tile[tx][ty + i*8]);
}

// ---------- QKV GEMM with FUSED RoPE + fragment-order epilogue ----------
// Epilogue staging: col-major [128 cols][stride 130] bf16. 130 ushorts = 65 dwords; 65 % 32 == 1,
// so lane-j scalar reads map to bank j%32 (2-way across 64 lanes = free). 8B vector accesses are
// split into 2x ushort2 (260B col stride is 4B- but not 8B-aligned).
#define CLDS_STRIDE 130
__global__ __launch_bounds__(256) void k_gemm_qkv(const ushort* __restrict__ A, const ushort* __restrict__ Bt,
                                                  const float* __restrict__ sintab,
                                                  ushort* __restrict__ Qf, ushort* __restrict__ Kf,
                                                  ushort* __restrict__ Vf, float qscale) {
    __shared__ __align__(16) char smem[33792];   // staging: A 2x8KB @0, B 2x8KB @16384; epilogue: [128][130] ushort
    int tid = threadIdx.x;
    int lane = tid & 63;
    int wave = tid >> 6;
    int wr = wave >> 1, wc = wave & 1;
    int m0 = blockIdx.y * 128, n0 = blockIdx.x * 128;
    int lr = lane & 15, lg = lane >> 4;

    f32x4 acc[4][4] = {};

    int arow = lane >> 2;        // 0..15 within chunk
    int kpart = (lane & 3) * 8;  // 0,8,16,24

    ushort* As = (ushort*)smem;            // [2][4096]
    ushort* Bs = (ushort*)(smem + 16384);  // [2][4096]

    // prologue: stage tile 0 into buf 0
    #pragma unroll
    for (int s = 0; s < 2; ++s) {
        int c = wave * 2 + s;
        gload_lds16(A  + (size_t)(m0 + c*16 + arow) * EMB + kpart, &As[c * 512]);
        gload_lds16(Bt + (size_t)(n0 + c*16 + arow) * EMB + kpart, &Bs[c * 512]);
    }
    __syncthreads();

    for (int t = 0; t < EMB/32; ++t) {
        int cur = t & 1;
        if (t + 1 < EMB/32) {
            int k1 = (t + 1) << 5;
            #pragma unroll
            for (int s = 0; s < 2; ++s) {
                int c = wave * 2 + s;
                gload_lds16(A  + (size_t)(m0 + c*16 + arow) * EMB + k1 + kpart, &As[(cur^1)*4096 + c*512]);
                gload_lds16(Bt + (size_t)(n0 + c*16 + arow) * EMB + k1 + kpart, &Bs[(cur^1)*4096 + c*512]);
            }
        }
        bf16x8 af[4], bfr[4];
        #pragma unroll
        for (int mt = 0; mt < 4; ++mt)
            af[mt] = *(const bf16x8*)&As[cur*4096 + (wr*64 + mt*16 + lr) * 32 + lg * 8];
        #pragma unroll
        for (int nt = 0; nt < 4; ++nt)
            bfr[nt] = *(const bf16x8*)&Bs[cur*4096 + (wc*64 + nt*16 + lr) * 32 + lg * 8];
        #pragma unroll
        for (int mt = 0; mt < 4; ++mt)
            #pragma unroll
            for (int nt = 0; nt < 4; ++nt)
                acc[mt][nt] = __builtin_amdgcn_mfma_f32_16x16x32_bf16(af[mt], bfr[nt], acc[mt][nt], 0, 0, 0);
        __syncthreads();
    }

    // ---- stage C tile to LDS, col-major [col][CLDS_STRIDE] bf16 (2x ushort2 per frag) ----
    ushort* clds = (ushort*)smem;
    #pragma unroll
    for (int mt = 0; mt < 4; ++mt) {
        #pragma unroll
        for (int nt = 0; nt < 4; ++nt) {
            int col = wc*64 + nt*16 + lr;
            int row = wr*64 + mt*16 + lg*4;
            ushort2 p01, p23;
            p01.x = f2bf(acc[mt][nt][0]); p01.y = f2bf(acc[mt][nt][1]);
            p23.x = f2bf(acc[mt][nt][2]); p23.y = f2bf(acc[mt][nt][3]);
            *(ushort2*)&clds[col*CLDS_STRIDE + row]     = p01;
            *(ushort2*)&clds[col*CLDS_STRIDE + row + 2] = p23;
        }
    }
    __syncthreads();

    int xt = blockIdx.x;          // 0..23
    int b = m0 >> 11;             // batch
    int pos0 = m0 & 2047;         // base position within batch

    if (xt < 20) {
        // RoPE (Q or K) -> fragment order
        int j = tid & 63;
        int rgrp = tid >> 6;
        ushort* dstb;
        float scl;
        if (xt < 16) { dstb = Qf + (size_t)((b*NH + xt) * 64) * 4096;      scl = qscale; }
        else         { dstb = Kf + (size_t)((b*NG + (xt-16)) * 64) * 4096; scl = 1.0f;   }
        #pragma unroll 4
        for (int it = 0; it < 32; ++it) {
            int row = rgrp + it*4;                 // 0..127
            int pos = pos0 + row;
            float a  = bf2f(clds[j*CLDS_STRIDE + row]);
            float bb = bf2f(clds[(j+64)*CLDS_STRIDE + row]);
            float sv = sintab[pos*64 + j] * scl;
            size_t idx = (size_t)(pos>>5)*4096 + (size_t)(j>>4)*512 + ((j>>3)&1)*256 + (pos&31)*8 + (j&7);
            dstb[idx]        = f2bf((a - bb) * sv);
            dstb[idx + 2048] = f2bf((bb + a) * sv);   // d=j+64 -> s+4 -> +4*512
        }
    } else {
        // V -> fragment order: Vf[((bg*64+step)*8 + dt*2+ks)*512 + lane*8 + e]
        int g = xt - 20;
        int bg = b*NG + g;
        int ln2 = tid & 31, hi2 = (tid >> 5) & 1, dt = tid >> 6;
        int colc = dt*32 + ln2;
        #pragma unroll
        for (int stp = 0; stp < 4; ++stp) {
            #pragma unroll
            for (int ks = 0; ks < 2; ++ks) {
                int rowb = stp*32 + ks*16 + hi2*8;
                union { ushort2 q[4]; bf16x8 v; } z;
                z.q[0] = *(ushort2*)&clds[colc*CLDS_STRIDE + rowb];
                z.q[1] = *(ushort2*)&clds[colc*CLDS_STRIDE + rowb + 2];
                z.q[2] = *(ushort2*)&clds[colc*CLDS_STRIDE + rowb + 4];
                z.q[3] = *(ushort2*)&clds[colc*CLDS_STRIDE + rowb + 6];
                int step_g = (pos0 >> 5) + stp;
                *(bf16x8*)(Vf + ((size_t)(bg*64 + step_g)*8 + dt*2 + ks) * 512 + (tid & 63) * 8) = z.v;
            }
        }
    }
}

// ---------- GEMM (f32 out + bias): double-buffered LDS, 1 barrier per K-step ----------
__global__ __launch_bounds__(256) void k_gemm_bt(const ushort* __restrict__ A, const ushort* __restrict__ Bt,
                                                 float* __restrict__ C, int M, int N, int K,
                                                 const float* __restrict__ bias) {
    __shared__ __align__(16) ushort As[2][128 * 32];
    __shared__ __align__(16) ushort Bs[2][128 * 32];
    int tid = threadIdx.x;
    int lane = tid & 63;
    int wave = tid >> 6;
    int wr = wave >> 1, wc = wave & 1;
    int m0 = blockIdx.y * 128, n0 = blockIdx.x * 128;
    int lr = lane & 15, lg = lane >> 4;

    f32x4 acc[4][4] = {};

    int arow = lane >> 2;
    int kpart = (lane & 3) * 8;

    int nsteps = K >> 5;

    #pragma unroll
    for (int s = 0; s < 2; ++s) {
        int c = wave * 2 + s;
        gload_lds16(A  + (size_t)(m0 + c*16 + arow) * K + kpart, &As[0][c * 512]);
        gload_lds16(Bt + (size_t)(n0 + c*16 + arow) * K + kpart, &Bs[0][c * 512]);
    }
    __syncthreads();

    for (int t = 0; t < nsteps; ++t) {
        int cur = t & 1;
        if (t + 1 < nsteps) {
            int k1 = (t + 1) << 5;
            #pragma unroll
            for (int s = 0; s < 2; ++s) {
                int c = wave * 2 + s;
                gload_lds16(A  + (size_t)(m0 + c*16 + arow) * K + k1 + kpart, &As[cur ^ 1][c * 512]);
                gload_lds16(Bt + (size_t)(n0 + c*16 + arow) * K + k1 + kpart, &Bs[cur ^ 1][c * 512]);
            }
        }
        bf16x8 af[4], bfr[4];
        #pragma unroll
        for (int mt = 0; mt < 4; ++mt)
            af[mt] = *(const bf16x8*)&As[cur][(wr*64 + mt*16 + lr) * 32 + lg * 8];
        #pragma unroll
        for (int nt = 0; nt < 4; ++nt)
            bfr[nt] = *(const bf16x8*)&Bs[cur][(wc*64 + nt*16 + lr) * 32 + lg * 8];
        #pragma unroll
        for (int mt = 0; mt < 4; ++mt)
            #pragma unroll
            for (int nt = 0; nt < 4; ++nt)
                acc[mt][nt] = __builtin_amdgcn_mfma_f32_16x16x32_bf16(af[mt], bfr[nt], acc[mt][nt], 0, 0, 0);
        __syncthreads();
    }

    #pragma unroll
    for (int mt = 0; mt < 4; ++mt) {
        #pragma unroll
        for (int nt = 0; nt < 4; ++nt) {
            int col = n0 + wc*64 + nt*16 + lr;
            float bv = bias ? bias[col] : 0.0f;
            #pragma unroll
            for (int r = 0; r < 4; ++r) {
                int row = m0 + wr*64 + mt*16 + lg*4 + r;
                C[(size_t)row * N + col] = acc[mt][nt][r] + bv;
            }
        }
    }
}

// ---------- flash attention v12: exact softmax, fragment-order operands ----------
__global__ __launch_bounds__(128) void k_attn12(const ushort* __restrict__ Qf, const ushort* __restrict__ Kf,
                                                const ushort* __restrict__ Vf, ushort* __restrict__ y) {
    __shared__ __align__(16) char smem[16640];
    char*  Qs  = smem;                         // bf16 fragment-order Q tile (8KB; overlaid post-loop)
    float* sOd = (float*)smem;                 // f32 [32][128] merge buffer
    float* sl  = (float*)(smem + 16384);

    int lane = threadIdx.x & 63;
    int w    = threadIdx.x >> 6;   // 0 or 1
    int B  = blockIdx.x;
    int bg = B & 7;                // XCD-local K/V set
    int within = B >> 3;           // 0..255
    int t  = 63 - (within >> 2);   // q-tile index, longest first within XCD
    int hh = within & 3;
    int b = bg >> 2, g = bg & 3, h = g * 4 + hh;
    int ln = lane & 31, hi = lane >> 5;
    int q0 = t * 32;

    // Q stage: 8KB fragment-order tile via global_load_lds (lane-linear dest)
    {
        const ushort* qf_g = Qf + ((size_t)((b*NH + h) * 64 + t)) * 4096;
        int tid = threadIdx.x;
        #pragma unroll
        for (int it = 0; it < 4; ++it)
            gload_lds16(qf_g + (it*128 + tid) * 8, Qs + it*2048 + w*1024);
    }
    __syncthreads();

    const ushort* kfb = Kf + (size_t)bg * 64 * 4096 + lane * 8;
    const ushort* vfb = Vf + (size_t)bg * 64 * 4096 + lane * 8;
    const char*   qsl = Qs + lane * 16;

    f32x16 od[4] = {};             // O: row q = (r&3)+8*(r>>2)+4*hi, col d = dt*32+ln
    float lsum = 0.0f;             // per q = ln (lanes l and l^32 hold same q)

    auto step = [&](int si, bool diag) {
        const ushort* kp = kfb + (size_t)si * 4096;
        const ushort* vp = vfb + (size_t)si * 4096;
        f32x16 st = {};
        #pragma unroll
        for (int s = 0; s < 8; ++s) {
            bf16x8 kf = *(const bf16x8*)(kp + s * 512);
            bf16x8 qf = *(const bf16x8*)(qsl + s * 1024);
            st = __builtin_amdgcn_mfma_f32_32x32x16_bf16(kf, qf, st, 0, 0, 0);
        }

        if (diag) {
            #pragma unroll
            for (int r = 0; r < 16; ++r) {
                int kl = (r & 3) + 8*(r >> 2) + 4*hi;
                if (kl > ln) st[r] = -1e30f;
            }
        }
        // P = exp2(S) in place (exact; masked entries -> 0)
        #pragma unroll
        for (int r = 0; r < 16; ++r) st[r] = exp2f(st[r]);
        // pairwise-tree row sum
        float s8[8];
        #pragma unroll
        for (int r = 0; r < 8; ++r) s8[r] = st[r] + st[r+8];
        #pragma unroll
        for (int r = 0; r < 4; ++r) s8[r] = s8[r] + s8[r+4];
        float ls = (s8[0] + s8[1]) + (s8[2] + s8[3]);
        lsum += ls + __shfl_xor(ls, 32, 64);

        // O += P.V, one ks-half at a time; V fragments coalesced
        #pragma unroll
        for (int ks = 0; ks < 2; ++ks) {
            uint32_t w0 = packbf(st[8*ks+0], st[8*ks+1]);
            uint32_t w1 = packbf(st[8*ks+2], st[8*ks+3]);
            uint32_t w2 = packbf(st[8*ks+4], st[8*ks+5]);
            uint32_t w3 = packbf(st[8*ks+6], st[8*ks+7]);
            uint32_t x0 = (uint32_t)__shfl_xor((int)w0, 32, 64);
            uint32_t x1 = (uint32_t)__shfl_xor((int)w1, 32, 64);
            uint32_t x2 = (uint32_t)__shfl_xor((int)w2, 32, 64);
            uint32_t x3 = (uint32_t)__shfl_xor((int)w3, 32, 64);
            bf16x8 pa = hi ? mkfrag(x2, x3, w2, w3) : mkfrag(w0, w1, x0, x1);
            #pragma unroll
            for (int dt = 0; dt < 4; ++dt) {
                bf16x8 vf = *(const bf16x8*)(vp + (dt*2 + ks) * 512);
                od[dt] = __builtin_amdgcn_mfma_f32_32x32x16_bf16(pa, vf, od[dt], 0, 0, 0);
            }
        }
    };

    for (int si = w; si < t; si += 2) step(si, false);
    if ((t & 1) == w) step(t, true);

    // ---- merge the two waves' partials (sOd overlays Qs: barrier first); pure add ----
    __syncthreads();
    if (w == 1) {
        #pragma unroll
        for (int r = 0; r < 16; ++r) {
            int ri = (r & 3) + 8*(r >> 2) + 4*hi;
            #pragma unroll
            for (int dt = 0; dt < 4; ++dt) sOd[ri*128 + dt*32 + ln] = od[dt][r];
        }
        if (hi == 0) sl[ln] = lsum;
    }
    __syncthreads();
    if (w == 0) {
        float inv = 1.0f / (lsum + sl[ln]);
        #pragma unroll
        for (int r = 0; r < 16; ++r) {
            int ri = (r & 3) + 8*(r >> 2) + 4*hi;
            float ivr = __shfl(inv, ri, 64);
            int row = q0 + ri;
            #pragma unroll
            for (int dt = 0; dt < 4; ++dt) {
                float v = (od[dt][r] + sOd[ri*128 + dt*32 + ln]) * ivr;
                y[((size_t)(b*CTX + row)) * (NH*HD) + h*HD + dt*32 + ln] = f2bf(v);
            }
        }
    }
}

// ---------- workspace layout (bytes) ----------
#define SIN_OFF   ((size_t)0)
#define XB_OFF    ((size_t)524288)
#define WT_OFF    ((size_t)17301504)
#define WOT_OFF   ((size_t)29884416)
#define QB_OFF    ((size_t)88604672)
#define KB_OFF    ((size_t)105381888)
#define VT_OFF    ((size_t)109576192)
#define YB_OFF    ((size_t)113770496)

extern "C" void kernel_launch(void* const* d_in, const int* in_sizes, int n_in,
                              void* d_out, int out_size, void* d_ws, size_t ws_size,
                              hipStream_t stream) {
    const float* x  = (const float*)d_in[0];
    const float* Wq = (const float*)d_in[1];
    const float* Wk = (const float*)d_in[2];
    const float* Wv = (const float*)d_in[3];
    const float* Wo = (const float*)d_in[4];
    const float* bo = (const float*)d_in[5];
    float* out = (float*)d_out;
    char* ws = (char*)d_ws;

    float*  sintab = (float*)(ws + SIN_OFF);
    ushort* xb     = (ushort*)(ws + XB_OFF);
    ushort* Wt     = (ushort*)(ws + WT_OFF);
    ushort* Wot    = (ushort*)(ws + WOT_OFF);
    ushort* Qf     = (ushort*)(ws + QB_OFF);
    ushort* Kf     = (ushort*)(ws + KB_OFF);
    ushort* Vf     = (ushort*)(ws + VT_OFF);
    ushort* yb     = (ushort*)(ws + YB_OFF);

    const float qscale = 0.08838834764831845f * 1.4426950408889634f;  // 1/sqrt(128) * log2(e)

    // 1. sin table
    k_sintab<<<512, 256, 0, stream>>>(sintab);
    // 2. x -> bf16
    k_cvt<<<(MROWS * EMB / 4) / 256, 256, 0, stream>>>((const float4*)x, (ushort4*)xb);
    // 3. all weight transposes (one launch)
    k_transpose_all<<<dim3(64, 64, 4), dim3(32, 8), 0, stream>>>(Wq, Wk, Wv, Wo, Wt, Wot);
    // 4. QKV GEMM with fused RoPE + fragment-order epilogue -> Qf, Kf, Vf directly
    k_gemm_qkv<<<dim3(NQK/128, MROWS/128), 256, 0, stream>>>(xb, Wt, sintab, Qf, Kf, Vf, qscale);
    // 5. attention (2048 blocks x 2 waves, XCD-local, exact softmax)
    k_attn12<<<2048, 128, 0, stream>>>(Qf, Kf, Vf, yb);
    // 6. out = y @ Wo + bo  (f32 out)
    k_gemm_bt<<<dim3(EMB/128, MROWS/128), 256, 0, stream>>>(yb, Wot, out, MROWS, EMB, EMB, bo);
}

// Round 17
// 206.819 us; speedup vs baseline: 1.0201x; 1.0201x over previous
//
#include <hip/hip_runtime.h>
#include <hip/hip_bf16.h>
#include <cstdint>
#include <cstddef>

// ---------- constants ----------
#define BATCH 2
#define CTX 2048
#define EMB 2048
#define NH 16
#define NG 4
#define HD 128
#define NQK (EMB + 2*NG*HD)   // 3072 combined QKV output cols
#define MROWS (BATCH*CTX)     // 4096

typedef __bf16 bf16x8 __attribute__((ext_vector_type(8)));
typedef float  f32x4  __attribute__((ext_vector_type(4)));
typedef float  f32x16 __attribute__((ext_vector_type(16)));

__device__ __forceinline__ ushort f2bf(float f) {
    uint32_t u = __float_as_uint(f);
    u += 0x7FFFu + ((u >> 16) & 1u);   // round-to-nearest-even
    return (ushort)(u >> 16);
}

__device__ __forceinline__ float bf2f(ushort u) {
    return __uint_as_float((uint32_t)u << 16);
}

__device__ __forceinline__ uint32_t packbf(float a, float b) {
    ushort lo = __builtin_bit_cast(ushort, (__bf16)a);
    ushort hi = __builtin_bit_cast(ushort, (__bf16)b);
    return (uint32_t)lo | ((uint32_t)hi << 16);
}

__device__ __forceinline__ bf16x8 mkfrag(uint32_t a, uint32_t b, uint32_t c, uint32_t d) {
    union { uint32_t u[4]; bf16x8 v; } z;
    z.u[0] = a; z.u[1] = b; z.u[2] = c; z.u[3] = d;
    return z.v;
}

__device__ __forceinline__ void gload_lds16(const void* g, void* l) {
    __builtin_amdgcn_global_load_lds((const __attribute__((address_space(1))) void*)g,
                                     (__attribute__((address_space(3))) void*)l, 16, 0, 0);
}

// ---------- sin table: sintab[pos][j], j in 0..63 ----------
__global__ __launch_bounds__(256) void k_sintab(float* __restrict__ sintab) {
    int t = blockIdx.x * 256 + threadIdx.x;   // 2048*64
    int j = t & 63, p = t >> 6;
    float theta = 1.0f / powf(10000.0f, (float)(2 * j) / 64.0f);
    sintab[t] = sinf((float)p * theta);
}

// ---------- f32 -> bf16 elementwise (4 per thread) ----------
__global__ __launch_bounds__(256) void k_cvt(const float4* __restrict__ src, ushort4* __restrict__ dst) {
    int i = blockIdx.x * 256 + threadIdx.x;
    float4 v = src[i];
    ushort4 o;
    o.x = f2bf(v.x); o.y = f2bf(v.y); o.z = f2bf(v.z); o.w = f2bf(v.w);
    dst[i] = o;
}

// ---------- all 4 weight transposes in one launch (z selects) ----------
__global__ __launch_bounds__(256) void k_transpose_all(const float* __restrict__ Wq, const float* __restrict__ Wk,
                                                       const float* __restrict__ Wv, const float* __restrict__ Wo,
                                                       ushort* __restrict__ Wt, ushort* __restrict__ Wot) {
    __shared__ float tile[32][33];
    int z = blockIdx.z;
    const float* src; ushort* dst; int src_ld, dst_ld, ncols;
    if (z == 0)      { src = Wq; dst = Wt;                              src_ld = EMB;   dst_ld = EMB; ncols = EMB; }
    else if (z == 1) { src = Wk; dst = Wt + (size_t)EMB * EMB;          src_ld = NG*HD; dst_ld = EMB; ncols = NG*HD; }
    else if (z == 2) { src = Wv; dst = Wt + (size_t)(EMB + NG*HD) * EMB; src_ld = NG*HD; dst_ld = EMB; ncols = NG*HD; }
    else             { src = Wo; dst = Wot;                             src_ld = EMB;   dst_ld = EMB; ncols = EMB; }
    int c0 = blockIdx.x * 32, r0 = blockIdx.y * 32;
    if (c0 >= ncols) return;
    int tx = threadIdx.x, ty = threadIdx.y;          // 32 x 8
    #pragma unroll
    for (int i = 0; i < 4; ++i)
        tile[ty + i*8][tx] = src[(size_t)(r0 + ty + i*8) * src_ld + c0 + tx];
    __syncthreads();
    #pragma unroll
    for (int i = 0; i < 4; ++i)
        dst[(size_t)(c0 + ty + i*8) * dst_ld + r0 + tx] = f2bf(tile[tx][ty + i*8]);
}

// ---------- QKV GEMM with FUSED RoPE + fragment-order epilogue ----------
// Main loop: unroll x2 (static buf offsets 0/4096), explicit pointer bumping, last-2-steps peel,
// XCD-bijective block swizzle (nwg=768, %8==0). Sync structure unchanged (1 barrier per K-step).
#define CLDS_STRIDE 130
__global__ __launch_bounds__(256) void k_gemm_qkv(const ushort* __restrict__ A, const ushort* __restrict__ Bt,
                                                  const float* __restrict__ sintab,
                                                  ushort* __restrict__ Qf, ushort* __restrict__ Kf,
                                                  ushort* __restrict__ Vf, float qscale) {
    __shared__ __align__(16) char smem[33792];   // staging: A 2x8KB @0, B 2x8KB @16384; epilogue: [128][130] ushort
    int tid = threadIdx.x;
    int lane = tid & 63;
    int wave = tid >> 6;
    int wr = wave >> 1, wc = wave & 1;

    // XCD-bijective swizzle of flattened block id
    int nbx = gridDim.x;                       // 24
    int id  = blockIdx.y * nbx + blockIdx.x;
    int cpx = (nbx * gridDim.y) >> 3;
    int sid = (id & 7) * cpx + (id >> 3);
    int bx = sid % nbx, by = sid / nbx;
    int m0 = by * 128, n0 = bx * 128;

    int lr = lane & 15, lg = lane >> 4;

    f32x4 acc[4][4] = {};

    int arow = lane >> 2;        // 0..15 within chunk
    int kpart = (lane & 3) * 8;  // 0,8,16,24

    ushort* As = (ushort*)smem;            // [2][4096]
    ushort* Bs = (ushort*)(smem + 16384);  // [2][4096]

    int c0s = (wave*2 + 0) * 512, c1s = (wave*2 + 1) * 512;
    const ushort* ga0 = A  + (size_t)(m0 + (wave*2+0)*16 + arow) * EMB + kpart;
    const ushort* ga1 = A  + (size_t)(m0 + (wave*2+1)*16 + arow) * EMB + kpart;
    const ushort* gb0 = Bt + (size_t)(n0 + (wave*2+0)*16 + arow) * EMB + kpart;
    const ushort* gb1 = Bt + (size_t)(n0 + (wave*2+1)*16 + arow) * EMB + kpart;

    auto stage = [&](int koff, int bufoff) {
        gload_lds16(ga0 + koff, &As[bufoff + c0s]);
        gload_lds16(ga1 + koff, &As[bufoff + c1s]);
        gload_lds16(gb0 + koff, &Bs[bufoff + c0s]);
        gload_lds16(gb1 + koff, &Bs[bufoff + c1s]);
    };
    auto compute = [&](int bufoff) {
        bf16x8 af[4], bfr[4];
        #pragma unroll
        for (int mt = 0; mt < 4; ++mt)
            af[mt] = *(const bf16x8*)&As[bufoff + (wr*64 + mt*16 + lr) * 32 + lg * 8];
        #pragma unroll
        for (int nt = 0; nt < 4; ++nt)
            bfr[nt] = *(const bf16x8*)&Bs[bufoff + (wc*64 + nt*16 + lr) * 32 + lg * 8];
        #pragma unroll
        for (int mt = 0; mt < 4; ++mt)
            #pragma unroll
            for (int nt = 0; nt < 4; ++nt)
                acc[mt][nt] = __builtin_amdgcn_mfma_f32_16x16x32_bf16(af[mt], bfr[nt], acc[mt][nt], 0, 0, 0);
    };

    const int nsteps = EMB / 32;   // 64 (even)
    stage(0, 0);
    __syncthreads();
    for (int t = 0; t + 2 < nsteps; t += 2) {
        stage(32, 4096);           // tile t+1 -> buf1
        compute(0);                // tile t
        __syncthreads();
        stage(64, 0);              // tile t+2 -> buf0
        compute(4096);             // tile t+1
        __syncthreads();
        ga0 += 64; ga1 += 64; gb0 += 64; gb1 += 64;
    }
    stage(32, 4096);               // tile nsteps-1 -> buf1
    compute(0);                    // tile nsteps-2
    __syncthreads();
    compute(4096);                 // tile nsteps-1
    __syncthreads();               // before epilogue LDS overlay

    // ---- stage C tile to LDS, col-major [col][CLDS_STRIDE] bf16 (2x ushort2 per frag) ----
    ushort* clds = (ushort*)smem;
    #pragma unroll
    for (int mt = 0; mt < 4; ++mt) {
        #pragma unroll
        for (int nt = 0; nt < 4; ++nt) {
            int col = wc*64 + nt*16 + lr;
            int row = wr*64 + mt*16 + lg*4;
            ushort2 p01, p23;
            p01.x = f2bf(acc[mt][nt][0]); p01.y = f2bf(acc[mt][nt][1]);
            p23.x = f2bf(acc[mt][nt][2]); p23.y = f2bf(acc[mt][nt][3]);
            *(ushort2*)&clds[col*CLDS_STRIDE + row]     = p01;
            *(ushort2*)&clds[col*CLDS_STRIDE + row + 2] = p23;
        }
    }
    __syncthreads();

    int xt = bx;                  // 0..23 (swizzled N-tile = head selector)
    int b = m0 >> 11;             // batch
    int pos0 = m0 & 2047;         // base position within batch

    if (xt < 20) {
        // RoPE (Q or K) -> fragment order
        int j = tid & 63;
        int rgrp = tid >> 6;
        ushort* dstb;
        float scl;
        if (xt < 16) { dstb = Qf + (size_t)((b*NH + xt) * 64) * 4096;      scl = qscale; }
        else         { dstb = Kf + (size_t)((b*NG + (xt-16)) * 64) * 4096; scl = 1.0f;   }
        #pragma unroll 4
        for (int it = 0; it < 32; ++it) {
            int row = rgrp + it*4;                 // 0..127
            int pos = pos0 + row;
            float a  = bf2f(clds[j*CLDS_STRIDE + row]);
            float bb = bf2f(clds[(j+64)*CLDS_STRIDE + row]);
            float sv = sintab[pos*64 + j] * scl;
            size_t idx = (size_t)(pos>>5)*4096 + (size_t)(j>>4)*512 + ((j>>3)&1)*256 + (pos&31)*8 + (j&7);
            dstb[idx]        = f2bf((a - bb) * sv);
            dstb[idx + 2048] = f2bf((bb + a) * sv);   // d=j+64 -> s+4 -> +4*512
        }
    } else {
        // V -> fragment order: Vf[((bg*64+step)*8 + dt*2+ks)*512 + lane*8 + e]
        int g = xt - 20;
        int bg = b*NG + g;
        int ln2 = tid & 31, hi2 = (tid >> 5) & 1, dt = tid >> 6;
        int colc = dt*32 + ln2;
        #pragma unroll
        for (int stp = 0; stp < 4; ++stp) {
            #pragma unroll
            for (int ks = 0; ks < 2; ++ks) {
                int rowb = stp*32 + ks*16 + hi2*8;
                union { ushort2 q[4]; bf16x8 v; } z;
                z.q[0] = *(ushort2*)&clds[colc*CLDS_STRIDE + rowb];
                z.q[1] = *(ushort2*)&clds[colc*CLDS_STRIDE + rowb + 2];
                z.q[2] = *(ushort2*)&clds[colc*CLDS_STRIDE + rowb + 4];
                z.q[3] = *(ushort2*)&clds[colc*CLDS_STRIDE + rowb + 6];
                int step_g = (pos0 >> 5) + stp;
                *(bf16x8*)(Vf + ((size_t)(bg*64 + step_g)*8 + dt*2 + ks) * 512 + (tid & 63) * 8) = z.v;
            }
        }
    }
}

// ---------- GEMM (f32 out + bias): unroll x2, pointer bump, peel, XCD swizzle ----------
__global__ __launch_bounds__(256) void k_gemm_bt(const ushort* __restrict__ A, const ushort* __restrict__ Bt,
                                                 float* __restrict__ C, int M, int N, int K,
                                                 const float* __restrict__ bias) {
    __shared__ __align__(16) ushort As[2][128 * 32];
    __shared__ __align__(16) ushort Bs[2][128 * 32];
    int tid = threadIdx.x;
    int lane = tid & 63;
    int wave = tid >> 6;
    int wr = wave >> 1, wc = wave & 1;

    // XCD-bijective swizzle (nwg % 8 == 0 for our grids)
    int nbx = gridDim.x;
    int id  = blockIdx.y * nbx + blockIdx.x;
    int cpx = (nbx * gridDim.y) >> 3;
    int sid = (id & 7) * cpx + (id >> 3);
    int bx = sid % nbx, by = sid / nbx;
    int m0 = by * 128, n0 = bx * 128;

    int lr = lane & 15, lg = lane >> 4;

    f32x4 acc[4][4] = {};

    int arow = lane >> 2;
    int kpart = (lane & 3) * 8;

    int c0s = (wave*2 + 0) * 512, c1s = (wave*2 + 1) * 512;
    const ushort* ga0 = A  + (size_t)(m0 + (wave*2+0)*16 + arow) * K + kpart;
    const ushort* ga1 = A  + (size_t)(m0 + (wave*2+1)*16 + arow) * K + kpart;
    const ushort* gb0 = Bt + (size_t)(n0 + (wave*2+0)*16 + arow) * K + kpart;
    const ushort* gb1 = Bt + (size_t)(n0 + (wave*2+1)*16 + arow) * K + kpart;

    auto stage = [&](int koff, int buf) {
        gload_lds16(ga0 + koff, &As[buf][c0s]);
        gload_lds16(ga1 + koff, &As[buf][c1s]);
        gload_lds16(gb0 + koff, &Bs[buf][c0s]);
        gload_lds16(gb1 + koff, &Bs[buf][c1s]);
    };
    auto compute = [&](int buf) {
        bf16x8 af[4], bfr[4];
        #pragma unroll
        for (int mt = 0; mt < 4; ++mt)
            af[mt] = *(const bf16x8*)&As[buf][(wr*64 + mt*16 + lr) * 32 + lg * 8];
        #pragma unroll
        for (int nt = 0; nt < 4; ++nt)
            bfr[nt] = *(const bf16x8*)&Bs[buf][(wc*64 + nt*16 + lr) * 32 + lg * 8];
        #pragma unroll
        for (int mt = 0; mt < 4; ++mt)
            #pragma unroll
            for (int nt = 0; nt < 4; ++nt)
                acc[mt][nt] = __builtin_amdgcn_mfma_f32_16x16x32_bf16(af[mt], bfr[nt], acc[mt][nt], 0, 0, 0);
    };

    int nsteps = K >> 5;           // even (64)
    stage(0, 0);
    __syncthreads();
    for (int t = 0; t + 2 < nsteps; t += 2) {
        stage(32, 1);
        compute(0);
        __syncthreads();
        stage(64, 0);
        compute(1);
        __syncthreads();
        ga0 += 64; ga1 += 64; gb0 += 64; gb1 += 64;
    }
    stage(32, 1);
    compute(0);
    __syncthreads();
    compute(1);

    #pragma unroll
    for (int mt = 0; mt < 4; ++mt) {
        #pragma unroll
        for (int nt = 0; nt < 4; ++nt) {
            int col = n0 + wc*64 + nt*16 + lr;
            float bv = bias ? bias[col] : 0.0f;
            #pragma unroll
            for (int r = 0; r < 4; ++r) {
                int row = m0 + wr*64 + mt*16 + lg*4 + r;
                C[(size_t)row * N + col] = acc[mt][nt][r] + bv;
            }
        }
    }
}

// ---------- flash attention v12: exact softmax, fragment-order operands (unchanged) ----------
__global__ __launch_bounds__(128) void k_attn12(const ushort* __restrict__ Qf, const ushort* __restrict__ Kf,
                                                const ushort* __restrict__ Vf, ushort* __restrict__ y) {
    __shared__ __align__(16) char smem[16640];
    char*  Qs  = smem;                         // bf16 fragment-order Q tile (8KB; overlaid post-loop)
    float* sOd = (float*)smem;                 // f32 [32][128] merge buffer
    float* sl  = (float*)(smem + 16384);

    int lane = threadIdx.x & 63;
    int w    = threadIdx.x >> 6;   // 0 or 1
    int B  = blockIdx.x;
    int bg = B & 7;                // XCD-local K/V set
    int within = B >> 3;           // 0..255
    int t  = 63 - (within >> 2);   // q-tile index, longest first within XCD
    int hh = within & 3;
    int b = bg >> 2, g = bg & 3, h = g * 4 + hh;
    int ln = lane & 31, hi = lane >> 5;
    int q0 = t * 32;

    // Q stage: 8KB fragment-order tile via global_load_lds (lane-linear dest)
    {
        const ushort* qf_g = Qf + ((size_t)((b*NH + h) * 64 + t)) * 4096;
        int tid = threadIdx.x;
        #pragma unroll
        for (int it = 0; it < 4; ++it)
            gload_lds16(qf_g + (it*128 + tid) * 8, Qs + it*2048 + w*1024);
    }
    __syncthreads();

    const ushort* kfb = Kf + (size_t)bg * 64 * 4096 + lane * 8;
    const ushort* vfb = Vf + (size_t)bg * 64 * 4096 + lane * 8;
    const char*   qsl = Qs + lane * 16;

    f32x16 od[4] = {};             // O: row q = (r&3)+8*(r>>2)+4*hi, col d = dt*32+ln
    float lsum = 0.0f;             // per q = ln (lanes l and l^32 hold same q)

    auto step = [&](int si, bool diag) {
        const ushort* kp = kfb + (size_t)si * 4096;
        const ushort* vp = vfb + (size_t)si * 4096;
        f32x16 st = {};
        #pragma unroll
        for (int s = 0; s < 8; ++s) {
            bf16x8 kf = *(const bf16x8*)(kp + s * 512);
            bf16x8 qf = *(const bf16x8*)(qsl + s * 1024);
            st = __builtin_amdgcn_mfma_f32_32x32x16_bf16(kf, qf, st, 0, 0, 0);
        }

        if (diag) {
            #pragma unroll
            for (int r = 0; r < 16; ++r) {
                int kl = (r & 3) + 8*(r >> 2) + 4*hi;
                if (kl > ln) st[r] = -1e30f;
            }
        }
        // P = exp2(S) in place (exact; masked entries -> 0)
        #pragma unroll
        for (int r = 0; r < 16; ++r) st[r] = exp2f(st[r]);
        // pairwise-tree row sum
        float s8[8];
        #pragma unroll
        for (int r = 0; r < 8; ++r) s8[r] = st[r] + st[r+8];
        #pragma unroll
        for (int r = 0; r < 4; ++r) s8[r] = s8[r] + s8[r+4];
        float ls = (s8[0] + s8[1]) + (s8[2] + s8[3]);
        lsum += ls + __shfl_xor(ls, 32, 64);

        // O += P.V, one ks-half at a time; V fragments coalesced
        #pragma unroll
        for (int ks = 0; ks < 2; ++ks) {
            uint32_t w0 = packbf(st[8*ks+0], st[8*ks+1]);
            uint32_t w1 = packbf(st[8*ks+2], st[8*ks+3]);
            uint32_t w2 = packbf(st[8*ks+4], st[8*ks+5]);
            uint32_t w3 = packbf(st[8*ks+6], st[8*ks+7]);
            uint32_t x0 = (uint32_t)__shfl_xor((int)w0, 32, 64);
            uint32_t x1 = (uint32_t)__shfl_xor((int)w1, 32, 64);
            uint32_t x2 = (uint32_t)__shfl_xor((int)w2, 32, 64);
            uint32_t x3 = (uint32_t)__shfl_xor((int)w3, 32, 64);
            bf16x8 pa = hi ? mkfrag(x2, x3, w2, w3) : mkfrag(w0, w1, x0, x1);
            #pragma unroll
            for (int dt = 0; dt < 4; ++dt) {
                bf16x8 vf = *(const bf16x8*)(vp + (dt*2 + ks) * 512);
                od[dt] = __builtin_amdgcn_mfma_f32_32x32x16_bf16(pa, vf, od[dt], 0, 0, 0);
            }
        }
    };

    for (int si = w; si < t; si += 2) step(si, false);
    if ((t & 1) == w) step(t, true);

    // ---- merge the two waves' partials (sOd overlays Qs: barrier first); pure add ----
    __syncthreads();
    if (w == 1) {
        #pragma unroll
        for (int r = 0; r < 16; ++r) {
            int ri = (r & 3) + 8*(r >> 2) + 4*hi;
            #pragma unroll
            for (int dt = 0; dt < 4; ++dt) sOd[ri*128 + dt*32 + ln] = od[dt][r];
        }
        if (hi == 0) sl[ln] = lsum;
    }
    __syncthreads();
    if (w == 0) {
        float inv = 1.0f / (lsum + sl[ln]);
        #pragma unroll
        for (int r = 0; r < 16; ++r) {
            int ri = (r & 3) + 8*(r >> 2) + 4*hi;
            float ivr = __shfl(inv, ri, 64);
            int row = q0 + ri;
            #pragma unroll
            for (int dt = 0; dt < 4; ++dt) {
                float v = (od[dt][r] + sOd[ri*128 + dt*32 + ln]) * ivr;
                y[((size_t)(b*CTX + row)) * (NH*HD) + h*HD + dt*32 + ln] = f2bf(v);
            }
        }
    }
}

// ---------- workspace layout (bytes) ----------
#define SIN_OFF   ((size_t)0)
#define XB_OFF    ((size_t)524288)
#define WT_OFF    ((size_t)17301504)
#define WOT_OFF   ((size_t)29884416)
#define QB_OFF    ((size_t)88604672)
#define KB_OFF    ((size_t)105381888)
#define VT_OFF    ((size_t)109576192)
#define YB_OFF    ((size_t)113770496)

extern "C" void kernel_launch(void* const* d_in, const int* in_sizes, int n_in,
                              void* d_out, int out_size, void* d_ws, size_t ws_size,
                              hipStream_t stream) {
    const float* x  = (const float*)d_in[0];
    const float* Wq = (const float*)d_in[1];
    const float* Wk = (const float*)d_in[2];
    const float* Wv = (const float*)d_in[3];
    const float* Wo = (const float*)d_in[4];
    const float* bo = (const float*)d_in[5];
    float* out = (float*)d_out;
    char* ws = (char*)d_ws;

    float*  sintab = (float*)(ws + SIN_OFF);
    ushort* xb     = (ushort*)(ws + XB_OFF);
    ushort* Wt     = (ushort*)(ws + WT_OFF);
    ushort* Wot    = (ushort*)(ws + WOT_OFF);
    ushort* Qf     = (ushort*)(ws + QB_OFF);
    ushort* Kf     = (ushort*)(ws + KB_OFF);
    ushort* Vf     = (ushort*)(ws + VT_OFF);
    ushort* yb     = (ushort*)(ws + YB_OFF);

    const float qscale = 0.08838834764831845f * 1.4426950408889634f;  // 1/sqrt(128) * log2(e)

    // 1. sin table
    k_sintab<<<512, 256, 0, stream>>>(sintab);
    // 2. x -> bf16
    k_cvt<<<(MROWS * EMB / 4) / 256, 256, 0, stream>>>((const float4*)x, (ushort4*)xb);
    // 3. all weight transposes (one launch)
    k_transpose_all<<<dim3(64, 64, 4), dim3(32, 8), 0, stream>>>(Wq, Wk, Wv, Wo, Wt, Wot);
    // 4. QKV GEMM with fused RoPE + fragment-order epilogue -> Qf, Kf, Vf directly
    k_gemm_qkv<<<dim3(NQK/128, MROWS/128), 256, 0, stream>>>(xb, Wt, sintab, Qf, Kf, Vf, qscale);
    // 5. attention (2048 blocks x 2 waves, XCD-local, exact softmax)
    k_attn12<<<2048, 128, 0, stream>>>(Qf, Kf, Vf, yb);
    // 6. out = y @ Wo + bo  (f32 out)
    k_gemm_bt<<<dim3(EMB/128, MROWS/128), 256, 0, stream>>>(yb, Wot, out, MROWS, EMB, EMB, bo);
}